// Round 1
// baseline (446.619 us; speedup 1.0000x reference)
//
#include <hip/hip_runtime.h>

#define NFEAT 128

// ---------- Wt[k][j] = W[j][k] (64 KB) ----------
__global__ void k_transpose(const float* __restrict__ W, float* __restrict__ Wt) {
    int i = blockIdx.x * 256 + threadIdx.x;
    if (i < NFEAT * NFEAT) {
        int r = i >> 7, c = i & 127;
        Wt[c * NFEAT + r] = W[i];
    }
}

// ---------- z = h @ W^T, s1 = z.w1, s2 = z.w2 ----------
// block = 256 threads: 8 row-groups (rg) x 32 col-groups (cg); 32 nodes/block,
// each thread computes a 4x4 (node x feature) register tile.
__global__ __launch_bounds__(256) void k_gemm(
    const float* __restrict__ h, const float* __restrict__ Wt,
    const float* __restrict__ attn_w,
    float* __restrict__ z, float* __restrict__ s1, float* __restrict__ s2, int n)
{
    __shared__ float hs[32][NFEAT];
    const int tid = threadIdx.x;
    const int cg = tid & 31;   // features cg*4 .. cg*4+3
    const int rg = tid >> 5;   // nodes rg*4 .. rg*4+3 within block
    const int nodeBase = blockIdx.x * 32;

    const float4* h4 = reinterpret_cast<const float4*>(h);
    float4* hs4 = reinterpret_cast<float4*>(&hs[0][0]);
    for (int t = tid; t < 32 * 32; t += 256) {
        int row = t >> 5, c4 = t & 31;
        int nn = nodeBase + row;
        hs4[t] = (nn < n) ? h4[(size_t)nn * 32 + c4] : make_float4(0.f, 0.f, 0.f, 0.f);
    }
    __syncthreads();

    const float4* Wt4 = reinterpret_cast<const float4*>(Wt);
    float acc[4][4];
#pragma unroll
    for (int r = 0; r < 4; ++r)
#pragma unroll
        for (int c = 0; c < 4; ++c) acc[r][c] = 0.f;

    for (int k0 = 0; k0 < NFEAT; k0 += 4) {
        float4 wv[4];
#pragma unroll
        for (int i = 0; i < 4; ++i) wv[i] = Wt4[(size_t)(k0 + i) * 32 + cg];
        float4 hv[4];
#pragma unroll
        for (int r = 0; r < 4; ++r)
            hv[r] = *reinterpret_cast<const float4*>(&hs[rg * 4 + r][k0]);
#pragma unroll
        for (int r = 0; r < 4; ++r) {
            float hk;
#pragma unroll
            for (int i = 0; i < 4; ++i) {
                hk = (i == 0) ? hv[r].x : (i == 1) ? hv[r].y : (i == 2) ? hv[r].z : hv[r].w;
                acc[r][0] += hk * wv[i].x;
                acc[r][1] += hk * wv[i].y;
                acc[r][2] += hk * wv[i].z;
                acc[r][3] += hk * wv[i].w;
            }
        }
    }

    const float4 aw1 = reinterpret_cast<const float4*>(attn_w)[cg];
    const float4 aw2 = reinterpret_cast<const float4*>(attn_w)[cg + 32];
    float4* z4 = reinterpret_cast<float4*>(z);

#pragma unroll
    for (int r = 0; r < 4; ++r) {
        int node = nodeBase + rg * 4 + r;
        bool valid = node < n;
        if (valid)
            z4[(size_t)node * 32 + cg] =
                make_float4(acc[r][0], acc[r][1], acc[r][2], acc[r][3]);
        float p1 = acc[r][0] * aw1.x + acc[r][1] * aw1.y + acc[r][2] * aw1.z + acc[r][3] * aw1.w;
        float p2 = acc[r][0] * aw2.x + acc[r][1] * aw2.y + acc[r][2] * aw2.z + acc[r][3] * aw2.w;
#pragma unroll
        for (int off = 16; off > 0; off >>= 1) {
            p1 += __shfl_xor(p1, off);
            p2 += __shfl_xor(p2, off);
        }
        if (cg == 0 && valid) { s1[node] = p1; s2[node] = p2; }
    }
}

// ---------- degree histogram ----------
__global__ void k_count(const int* __restrict__ dst, int* __restrict__ counts, int e) {
    int i = blockIdx.x * 256 + threadIdx.x;
    if (i < e) atomicAdd(&counts[dst[i]], 1);
}

// ---------- 3-phase exclusive scan of counts -> row_start ----------
__global__ __launch_bounds__(256) void k_scan_a(const int* __restrict__ counts,
                                                int* __restrict__ row_start,
                                                int* __restrict__ blocksums, int n)
{
    __shared__ int wsum[4];
    int tid = threadIdx.x;
    int i = blockIdx.x * 256 + tid;
    int v = (i < n) ? counts[i] : 0;
    int lane = tid & 63, wave = tid >> 6;
    int x = v;
#pragma unroll
    for (int off = 1; off < 64; off <<= 1) {
        int t = __shfl_up(x, off);
        if (lane >= off) x += t;
    }
    if (lane == 63) wsum[wave] = x;
    __syncthreads();
    int base = 0;
    for (int w = 0; w < wave; ++w) base += wsum[w];
    if (i < n) row_start[i] = base + x - v;
    if (tid == 255) blocksums[blockIdx.x] = base + x;
}

__global__ __launch_bounds__(256) void k_scan_b(int* __restrict__ blocksums,
                                                int* __restrict__ total_out, int nb)
{
    __shared__ int wsum[4];
    int tid = threadIdx.x;
    int v = (tid < nb) ? blocksums[tid] : 0;
    int lane = tid & 63, wave = tid >> 6;
    int x = v;
#pragma unroll
    for (int off = 1; off < 64; off <<= 1) {
        int t = __shfl_up(x, off);
        if (lane >= off) x += t;
    }
    if (lane == 63) wsum[wave] = x;
    __syncthreads();
    int base = 0;
    for (int w = 0; w < wave; ++w) base += wsum[w];
    if (tid < nb) blocksums[tid] = base + x - v;
    if (tid == 255) total_out[0] = base + x;
}

__global__ void k_scan_c(int* __restrict__ row_start, const int* __restrict__ blocksums, int n) {
    int i = blockIdx.x * 256 + threadIdx.x;
    if (i < n) row_start[i] += blocksums[blockIdx.x];
}

// ---------- scatter edges into CSR slots, packed (etype<<16)|src ----------
__global__ void k_scatter(const int* __restrict__ src, const int* __restrict__ dst,
                          const int* __restrict__ etype,
                          const int* __restrict__ row_start, int* __restrict__ cursor,
                          unsigned int* __restrict__ edge_list, int e)
{
    int i = blockIdx.x * 256 + threadIdx.x;
    if (i < e) {
        int d = dst[i];
        int pos = row_start[d] + atomicAdd(&cursor[d], 1);
        edge_list[pos] = (unsigned int)src[i] | ((unsigned int)etype[i] << 16);
    }
}

// ---------- per-node softmax + weighted aggregation; 1 wave = 1 node ----------
__global__ __launch_bounds__(256) void k_aggregate(
    const float* __restrict__ z, const float* __restrict__ s1, const float* __restrict__ s2,
    const float* __restrict__ rel_emb, const float* __restrict__ bias,
    const int* __restrict__ row_start, const unsigned int* __restrict__ edge_list,
    float* __restrict__ out, int n)
{
    const int wave = threadIdx.x >> 6;
    const int lane = threadIdx.x & 63;
    const int node = blockIdx.x * 4 + wave;
    if (node >= n) return;

    const int beg = row_start[node];
    const int end = row_start[node + 1];

    const float2 bias2 = reinterpret_cast<const float2*>(bias)[lane];
    float ox = bias2.x, oy = bias2.y;

    if (beg < end) {
        const float s2n = s2[node];
        // pass 1: exact max (wave-uniform scalar loop)
        float m = -__builtin_inff();
        for (int k = beg; k < end; ++k) {
            unsigned int pk = edge_list[k];
            float ev = s1[pk & 0xFFFFu] + s2n;
            ev = ev > 0.f ? ev : 0.01f * ev;
            m = fmaxf(m, ev);
        }
        // pass 2: den + weighted gather-accumulate (independent iterations)
        const float2* zv = reinterpret_cast<const float2*>(z);
        float den = 0.f, ax = 0.f, ay = 0.f;
        for (int k = beg; k < end; ++k) {
            unsigned int pk = edge_list[k];
            int s = pk & 0xFFFFu;
            float ev = s1[s] + s2n;
            ev = ev > 0.f ? ev : 0.01f * ev;
            float p = __expf(ev - m);
            den += p;
            float w = rel_emb[pk >> 16] * p;
            float2 zr = zv[(size_t)s * 64 + lane];
            ax += w * zr.x;
            ay += w * zr.y;
        }
        float inv = 1.f / den;
        ox += ax * inv;
        oy += ay * inv;
    }
    reinterpret_cast<float2*>(out)[(size_t)node * 64 + lane] = make_float2(ox, oy);
}

extern "C" void kernel_launch(void* const* d_in, const int* in_sizes, int n_in,
                              void* d_out, int out_size, void* d_ws, size_t ws_size,
                              hipStream_t stream) {
    const float* h      = (const float*)d_in[0];
    const float* W      = (const float*)d_in[1];
    const float* attn_w = (const float*)d_in[2];
    const float* rel    = (const float*)d_in[3];
    const float* bias   = (const float*)d_in[4];
    const int*   src    = (const int*)d_in[5];
    const int*   dst    = (const int*)d_in[6];
    const int*   etype  = (const int*)d_in[7];
    const int n = in_sizes[0] / NFEAT;   // 50000
    const int e = in_sizes[5];           // 1600000
    float* out = (float*)d_out;

    // workspace layout
    char* p = (char*)d_ws;
    float* z  = (float*)p;                 p += (size_t)n * NFEAT * 4;
    float* s1 = (float*)p;                 p += (size_t)n * 4;
    float* s2 = (float*)p;                 p += (size_t)n * 4;
    float* Wt = (float*)p;                 p += (size_t)NFEAT * NFEAT * 4;
    int* row_start = (int*)p;              p += (size_t)(n + 1) * 4;
    int* counts    = (int*)p;              p += (size_t)n * 4;
    int* cursor    = (int*)p;              p += (size_t)n * 4;
    int* blocksums = (int*)p;              p += 256 * 4;
    unsigned int* edge_list = (unsigned int*)p;  p += (size_t)e * 4;

    hipMemsetAsync(counts, 0, (size_t)n * 2 * sizeof(int), stream);  // counts + cursor

    k_transpose<<<(NFEAT * NFEAT + 255) / 256, 256, 0, stream>>>(W, Wt);
    k_gemm<<<(n + 31) / 32, 256, 0, stream>>>(h, Wt, attn_w, z, s1, s2, n);
    k_count<<<(e + 255) / 256, 256, 0, stream>>>(dst, counts, e);
    int nb = (n + 255) / 256;
    k_scan_a<<<nb, 256, 0, stream>>>(counts, row_start, blocksums, n);
    k_scan_b<<<1, 256, 0, stream>>>(blocksums, row_start + n, nb);
    k_scan_c<<<nb, 256, 0, stream>>>(row_start, blocksums, n);
    k_scatter<<<(e + 255) / 256, 256, 0, stream>>>(src, dst, etype, row_start, cursor, edge_list, e);
    k_aggregate<<<(n + 3) / 4, 256, 0, stream>>>(z, s1, s2, rel, bias, row_start, edge_list, out, n);
}

// Round 2
// 347.433 us; speedup vs baseline: 1.2855x; 1.2855x over previous
//
#include <hip/hip_runtime.h>

#define NFEAT 128

// ---------- Wt[k][j] = W[j][k] (64 KB) ----------
__global__ void k_transpose(const float* __restrict__ W, float* __restrict__ Wt) {
    int i = blockIdx.x * 256 + threadIdx.x;
    if (i < NFEAT * NFEAT) {
        int r = i >> 7, c = i & 127;
        Wt[c * NFEAT + r] = W[i];
    }
}

// ---------- z = h @ W^T, s1 = z.w1, s2 = z.w2 ----------
__global__ __launch_bounds__(256) void k_gemm(
    const float* __restrict__ h, const float* __restrict__ Wt,
    const float* __restrict__ attn_w,
    float* __restrict__ z, float* __restrict__ s1, float* __restrict__ s2, int n)
{
    __shared__ float hs[32][NFEAT];
    const int tid = threadIdx.x;
    const int cg = tid & 31;   // features cg*4 .. cg*4+3
    const int rg = tid >> 5;   // nodes rg*4 .. rg*4+3 within block
    const int nodeBase = blockIdx.x * 32;

    const float4* h4 = reinterpret_cast<const float4*>(h);
    float4* hs4 = reinterpret_cast<float4*>(&hs[0][0]);
    for (int t = tid; t < 32 * 32; t += 256) {
        int row = t >> 5, c4 = t & 31;
        int nn = nodeBase + row;
        hs4[t] = (nn < n) ? h4[(size_t)nn * 32 + c4] : make_float4(0.f, 0.f, 0.f, 0.f);
    }
    __syncthreads();

    const float4* Wt4 = reinterpret_cast<const float4*>(Wt);
    float acc[4][4];
#pragma unroll
    for (int r = 0; r < 4; ++r)
#pragma unroll
        for (int c = 0; c < 4; ++c) acc[r][c] = 0.f;

    for (int k0 = 0; k0 < NFEAT; k0 += 4) {
        float4 wv[4];
#pragma unroll
        for (int i = 0; i < 4; ++i) wv[i] = Wt4[(size_t)(k0 + i) * 32 + cg];
        float4 hv[4];
#pragma unroll
        for (int r = 0; r < 4; ++r)
            hv[r] = *reinterpret_cast<const float4*>(&hs[rg * 4 + r][k0]);
#pragma unroll
        for (int r = 0; r < 4; ++r) {
            float hk;
#pragma unroll
            for (int i = 0; i < 4; ++i) {
                hk = (i == 0) ? hv[r].x : (i == 1) ? hv[r].y : (i == 2) ? hv[r].z : hv[r].w;
                acc[r][0] += hk * wv[i].x;
                acc[r][1] += hk * wv[i].y;
                acc[r][2] += hk * wv[i].z;
                acc[r][3] += hk * wv[i].w;
            }
        }
    }

    const float4 aw1 = reinterpret_cast<const float4*>(attn_w)[cg];
    const float4 aw2 = reinterpret_cast<const float4*>(attn_w)[cg + 32];
    float4* z4 = reinterpret_cast<float4*>(z);

#pragma unroll
    for (int r = 0; r < 4; ++r) {
        int node = nodeBase + rg * 4 + r;
        bool valid = node < n;
        if (valid)
            z4[(size_t)node * 32 + cg] =
                make_float4(acc[r][0], acc[r][1], acc[r][2], acc[r][3]);
        float p1 = acc[r][0] * aw1.x + acc[r][1] * aw1.y + acc[r][2] * aw1.z + acc[r][3] * aw1.w;
        float p2 = acc[r][0] * aw2.x + acc[r][1] * aw2.y + acc[r][2] * aw2.z + acc[r][3] * aw2.w;
#pragma unroll
        for (int off = 16; off > 0; off >>= 1) {
            p1 += __shfl_xor(p1, off);
            p2 += __shfl_xor(p2, off);
        }
        if (cg == 0 && valid) { s1[node] = p1; s2[node] = p2; }
    }
}

// ---------- degree histogram ----------
__global__ void k_count(const int* __restrict__ dst, int* __restrict__ counts, int e) {
    int i = blockIdx.x * 256 + threadIdx.x;
    if (i < e) atomicAdd(&counts[dst[i]], 1);
}

// ---------- 3-phase exclusive scan of counts -> row_start ----------
__global__ __launch_bounds__(256) void k_scan_a(const int* __restrict__ counts,
                                                int* __restrict__ row_start,
                                                int* __restrict__ blocksums, int n)
{
    __shared__ int wsum[4];
    int tid = threadIdx.x;
    int i = blockIdx.x * 256 + tid;
    int v = (i < n) ? counts[i] : 0;
    int lane = tid & 63, wave = tid >> 6;
    int x = v;
#pragma unroll
    for (int off = 1; off < 64; off <<= 1) {
        int t = __shfl_up(x, off);
        if (lane >= off) x += t;
    }
    if (lane == 63) wsum[wave] = x;
    __syncthreads();
    int base = 0;
    for (int w = 0; w < wave; ++w) base += wsum[w];
    if (i < n) row_start[i] = base + x - v;
    if (tid == 255) blocksums[blockIdx.x] = base + x;
}

__global__ __launch_bounds__(256) void k_scan_b(int* __restrict__ blocksums,
                                                int* __restrict__ total_out, int nb)
{
    __shared__ int wsum[4];
    int tid = threadIdx.x;
    int v = (tid < nb) ? blocksums[tid] : 0;
    int lane = tid & 63, wave = tid >> 6;
    int x = v;
#pragma unroll
    for (int off = 1; off < 64; off <<= 1) {
        int t = __shfl_up(x, off);
        if (lane >= off) x += t;
    }
    if (lane == 63) wsum[wave] = x;
    __syncthreads();
    int base = 0;
    for (int w = 0; w < wave; ++w) base += wsum[w];
    if (tid < nb) blocksums[tid] = base + x - v;
    if (tid == 255) total_out[0] = base + x;
}

// adds block offsets AND initializes cursor = row_start (saves a gather in scatter)
__global__ void k_scan_c(int* __restrict__ row_start, int* __restrict__ cursor,
                         const int* __restrict__ blocksums, int n) {
    int i = blockIdx.x * 256 + threadIdx.x;
    if (i < n) {
        int v = row_start[i] + blocksums[blockIdx.x];
        row_start[i] = v;
        cursor[i] = v;
    }
}

// ---------- scatter edges into CSR slots, packed (etype<<16)|src ----------
__global__ void k_scatter(const int* __restrict__ src, const int* __restrict__ dst,
                          const int* __restrict__ etype,
                          int* __restrict__ cursor,
                          unsigned int* __restrict__ edge_list, int e)
{
    int i = blockIdx.x * 256 + threadIdx.x;
    if (i < e) {
        int pos = atomicAdd(&cursor[dst[i]], 1);
        edge_list[pos] = (unsigned int)src[i] | ((unsigned int)etype[i] << 16);
    }
}

// ---------- per-node softmax + weighted aggregation; 1 wave = 1 node ----------
// Phase 1 (wave-parallel over edges): each lane owns edge beg+lane, computes
// leaky(s1[src]+s2[dst]); shfl-reduce max and den. Phase 2: per-edge (src,w)
// staged in wave-local LDS; gather loop does 2 edges/iter (half-wave x float4).
__global__ __launch_bounds__(256) void k_aggregate(
    const float* __restrict__ z, const float* __restrict__ s1, const float* __restrict__ s2,
    const float* __restrict__ rel_emb, const float* __restrict__ bias,
    const int* __restrict__ row_start, const unsigned int* __restrict__ edge_list,
    float* __restrict__ out, int n)
{
    __shared__ uint2 lds_ws[4][64];   // (src, w-bits) per edge of current chunk
    const int wv   = threadIdx.x >> 6;
    const int lane = threadIdx.x & 63;
    const int node = blockIdx.x * 4 + wv;
    if (node >= n) return;

    const int beg = row_start[node];
    const int end = row_start[node + 1];
    const int deg = end - beg;
    const int half = lane >> 5;   // which edge of the pair
    const int q    = lane & 31;   // float4 index within the 128-feat row

    float4 acc = make_float4(0.f, 0.f, 0.f, 0.f);
    const float4* z4 = reinterpret_cast<const float4*>(z);

    if (deg > 0) {
        const float s2n = s2[node];

        if (deg <= 64) {
            // ---- fast path: one edge per lane, everything stays in registers
            unsigned int pk = 0;
            float ev = -3.4e38f;
            const bool has = lane < deg;
            if (has) {
                pk = edge_list[beg + lane];
                ev = s1[pk & 0xFFFFu] + s2n;
                ev = ev > 0.f ? ev : 0.01f * ev;
            }
            float m = ev;
#pragma unroll
            for (int off = 32; off > 0; off >>= 1)
                m = fmaxf(m, __shfl_xor(m, off));
            float p = has ? __expf(ev - m) : 0.f;
            float den = p;
#pragma unroll
            for (int off = 32; off > 0; off >>= 1)
                den += __shfl_xor(den, off);
            const float inv = 1.f / den;
            if (has)
                lds_ws[wv][lane] = make_uint2(pk & 0xFFFFu,
                                              __float_as_uint(rel_emb[pk >> 16] * p * inv));
#pragma unroll 2
            for (int j = half; j < deg; j += 2) {
                uint2 t = lds_ws[wv][j];
                float w = __uint_as_float(t.y);
                float4 zr = z4[(size_t)t.x * 32 + q];
                acc.x += w * zr.x; acc.y += w * zr.y;
                acc.z += w * zr.z; acc.w += w * zr.w;
            }
        } else {
            // ---- rare path: degree > 64, chunked
            float mymax = -3.4e38f;
            for (int k = beg + lane; k < end; k += 64) {
                unsigned int pk = edge_list[k];
                float ev = s1[pk & 0xFFFFu] + s2n;
                ev = ev > 0.f ? ev : 0.01f * ev;
                mymax = fmaxf(mymax, ev);
            }
#pragma unroll
            for (int off = 32; off > 0; off >>= 1)
                mymax = fmaxf(mymax, __shfl_xor(mymax, off));
            float mysum = 0.f;
            for (int k = beg + lane; k < end; k += 64) {
                unsigned int pk = edge_list[k];
                float ev = s1[pk & 0xFFFFu] + s2n;
                ev = ev > 0.f ? ev : 0.01f * ev;
                mysum += __expf(ev - mymax);
            }
#pragma unroll
            for (int off = 32; off > 0; off >>= 1)
                mysum += __shfl_xor(mysum, off);
            const float inv = 1.f / mysum;

            for (int cb = beg; cb < end; cb += 64) {
                int k = cb + lane;
                if (k < end) {
                    unsigned int pk = edge_list[k];
                    int s = pk & 0xFFFFu;
                    float ev = s1[s] + s2n;
                    ev = ev > 0.f ? ev : 0.01f * ev;
                    lds_ws[wv][lane] = make_uint2((unsigned)s,
                        __float_as_uint(rel_emb[pk >> 16] * __expf(ev - mymax) * inv));
                }
                int cnt = min(64, end - cb);
#pragma unroll 2
                for (int j = half; j < cnt; j += 2) {
                    uint2 t = lds_ws[wv][j];
                    float w = __uint_as_float(t.y);
                    float4 zr = z4[(size_t)t.x * 32 + q];
                    acc.x += w * zr.x; acc.y += w * zr.y;
                    acc.z += w * zr.z; acc.w += w * zr.w;
                }
            }
        }
        // cross-half reduce: both halves end with the full edge sum
        acc.x += __shfl_xor(acc.x, 32);
        acc.y += __shfl_xor(acc.y, 32);
        acc.z += __shfl_xor(acc.z, 32);
        acc.w += __shfl_xor(acc.w, 32);
    }

    if (half == 0) {
        float4 b = reinterpret_cast<const float4*>(bias)[q];
        reinterpret_cast<float4*>(out)[(size_t)node * 32 + q] =
            make_float4(acc.x + b.x, acc.y + b.y, acc.z + b.z, acc.w + b.w);
    }
}

extern "C" void kernel_launch(void* const* d_in, const int* in_sizes, int n_in,
                              void* d_out, int out_size, void* d_ws, size_t ws_size,
                              hipStream_t stream) {
    const float* h      = (const float*)d_in[0];
    const float* W      = (const float*)d_in[1];
    const float* attn_w = (const float*)d_in[2];
    const float* rel    = (const float*)d_in[3];
    const float* bias   = (const float*)d_in[4];
    const int*   src    = (const int*)d_in[5];
    const int*   dst    = (const int*)d_in[6];
    const int*   etype  = (const int*)d_in[7];
    const int n = in_sizes[0] / NFEAT;   // 50000
    const int e = in_sizes[5];           // 1600000
    float* out = (float*)d_out;

    // workspace layout
    char* p = (char*)d_ws;
    float* z  = (float*)p;                 p += (size_t)n * NFEAT * 4;
    float* s1 = (float*)p;                 p += (size_t)n * 4;
    float* s2 = (float*)p;                 p += (size_t)n * 4;
    float* Wt = (float*)p;                 p += (size_t)NFEAT * NFEAT * 4;
    int* row_start = (int*)p;              p += (size_t)(n + 1) * 4;
    int* counts    = (int*)p;              p += (size_t)n * 4;
    int* cursor    = (int*)p;              p += (size_t)n * 4;
    int* blocksums = (int*)p;              p += 256 * 4;
    unsigned int* edge_list = (unsigned int*)p;  p += (size_t)e * 4;

    hipMemsetAsync(counts, 0, (size_t)n * sizeof(int), stream);

    k_transpose<<<(NFEAT * NFEAT + 255) / 256, 256, 0, stream>>>(W, Wt);
    k_gemm<<<(n + 31) / 32, 256, 0, stream>>>(h, Wt, attn_w, z, s1, s2, n);
    k_count<<<(e + 255) / 256, 256, 0, stream>>>(dst, counts, e);
    int nb = (n + 255) / 256;
    k_scan_a<<<nb, 256, 0, stream>>>(counts, row_start, blocksums, n);
    k_scan_b<<<1, 256, 0, stream>>>(blocksums, row_start + n, nb);
    k_scan_c<<<nb, 256, 0, stream>>>(row_start, cursor, blocksums, n);
    k_scatter<<<(e + 255) / 256, 256, 0, stream>>>(src, dst, etype, cursor, edge_list, e);
    k_aggregate<<<(n + 3) / 4, 256, 0, stream>>>(z, s1, s2, rel, bias, row_start, edge_list, out, n);
}